// Round 10
// baseline (159.589 us; speedup 1.0000x reference)
//
#include <hip/hip_runtime.h>
#include <hip/hip_cooperative_groups.h>
#include <cstddef>

namespace cg = cooperative_groups;

// Problem constants
#define Bsz 2
#define Lr  2048
#define Dr  1024
#define Nr  16
#define M_ROWS (Bsz*Lr)          // 4096
#define NPAD   1088              // padded (W_dt | W_B | W_C | zeros), 17 tiles of 64
#define CHUNK  32
#define NCH    (Lr/CHUNK)        // 64

#define BM 64
#define BN 64
#define BK 64
#define NK (Dr/BK)               // 16 K-iterations

typedef __attribute__((ext_vector_type(8))) __bf16 bf16x8;
typedef __attribute__((ext_vector_type(4))) float floatx4;

__device__ __forceinline__ unsigned short f2bf(float f) {
    unsigned u = __float_as_uint(f);
    u += 0x7fffu + ((u >> 16) & 1u);
    return (unsigned short)(u >> 16);
}

__device__ __forceinline__ float bf2f(unsigned short u) {
    return __uint_as_float(((unsigned)u) << 16);
}

__device__ __forceinline__ float softplus_f(float x) {
    // abs threshold is 0.905 -> fast log is fine
    if (x > 0.f) return x + __logf(1.f + __expf(-x));
    return __logf(1.f + __expf(x));
}

__device__ __forceinline__ void gload_lds16(const unsigned short* g, unsigned short* l) {
    __builtin_amdgcn_global_load_lds((const __attribute__((address_space(1))) void*)g,
                                     (__attribute__((address_space(3))) void*)l, 16, 0, 0);
}

// ---------------- K0: fused LayerNorm (blocks 0..4095) + weight-pack (rest) ----------------
__global__ __launch_bounds__(256) void ln_pack_kernel(const float* __restrict__ x,
                                                      const float* __restrict__ gamma,
                                                      const float* __restrict__ beta,
                                                      unsigned short* __restrict__ xnb,
                                                      const float* __restrict__ Wdt,
                                                      const float* __restrict__ WB,
                                                      const float* __restrict__ WC,
                                                      unsigned short* __restrict__ Wcat) {
    if (blockIdx.x >= M_ROWS) {
        int i = (blockIdx.x - M_ROWS) * 256 + threadIdx.x;  // over NPAD*Dr
        int row = i >> 10;
        int col = i & 1023;
        float v;
        if (row < Dr)                 v = Wdt[i];
        else if (row < Dr + Nr)       v = WB[(row - Dr) * Dr + col];
        else if (row < Dr + 2*Nr)     v = WC[(row - Dr - Nr) * Dr + col];
        else                          v = 0.f;
        Wcat[i] = f2bf(v);
        return;
    }
    int row = blockIdx.x;
    int tid = threadIdx.x;
    const float4* xr = (const float4*)(x + (size_t)row * Dr);
    float4 v = xr[tid];
    float s  = v.x + v.y + v.z + v.w;
    float ss = v.x*v.x + v.y*v.y + v.z*v.z + v.w*v.w;
    #pragma unroll
    for (int off = 32; off > 0; off >>= 1) {
        s  += __shfl_down(s, off);
        ss += __shfl_down(ss, off);
    }
    __shared__ float red[8];
    int wid = tid >> 6;
    if ((tid & 63) == 0) { red[wid*2] = s; red[wid*2+1] = ss; }
    __syncthreads();
    if (tid == 0) {
        float S = 0.f, SS = 0.f;
        #pragma unroll
        for (int w = 0; w < 4; w++) { S += red[w*2]; SS += red[w*2+1]; }
        float mu  = S * (1.f/Dr);
        float var = SS * (1.f/Dr) - mu*mu;
        red[0] = mu;
        red[1] = rsqrtf(var + 1e-5f);
    }
    __syncthreads();
    float mu = red[0], rs = red[1];
    float4 g = ((const float4*)gamma)[tid], bt = ((const float4*)beta)[tid];
    float4 o;
    o.x = (v.x - mu) * rs * g.x + bt.x;
    o.y = (v.y - mu) * rs * g.y + bt.y;
    o.z = (v.z - mu) * rs * g.z + bt.z;
    o.w = (v.w - mu) * rs * g.w + bt.w;
    ushort4 ob;
    ob.x = f2bf(o.x); ob.y = f2bf(o.y); ob.z = f2bf(o.z); ob.w = f2bf(o.w);
    ((ushort4*)(xnb + (size_t)row * Dr))[tid] = ob;
}

// ---------------- K2: MFMA GEMM [M_ROWS x NPAD] = xnb @ Wcat^T ----------------
// R8 skeleton (4-wave 64x64, 2-barrier, DMA staging, XCD swizzle, k-stagger)
// upgraded: BK=64 (half the barrier drains: 16 iters) and XOR-SWIZZLED LDS.
// global_load_lds forces LDS slot = wave_base + lane*16, but WHICH global
// chunk a lane stages is ours: slot (row, cs) holds global chunk cs^(row&7).
// Frag reads then hit 8 distinct 4-bank groups per quarter-wave (2-way = free)
// instead of the stride-32 layout's 8-way conflict (R8: 1.1M conflict cycles).
// dt stored bf16 (halves write traffic; scans read bf16).
__global__ __launch_bounds__(256) void gemm_kernel(const unsigned short* __restrict__ xnb,
                                                   const unsigned short* __restrict__ w,
                                                   const float* __restrict__ b_dt,
                                                   unsigned short* __restrict__ dt,
                                                   float* __restrict__ bin,
                                                   float* __restrict__ cin) {
    __shared__ unsigned short As[BM * BK];  // 8 KB, swizzled [64 rows][8 slots of 8]
    __shared__ unsigned short Bs[BN * BK];  // 8 KB
    int tid  = threadIdx.x;
    int wave = tid >> 6;
    int lane = tid & 63;
    int lm   = lane & 15;
    int quad = lane >> 4;
    int bid  = blockIdx.x;             // 1088 blocks = 8 XCD-lanes x 136
    int xcd  = bid & 7;
    int j0   = bid >> 3;               // 0..135
    int nt   = j0 % 17;
    int mt   = (j0 / 17) * 8 + xcd;    // 0..63
    int Mb = mt * BM;
    int Nb = nt * BN;
    int wm = (wave >> 1) * 32;
    int wn = (wave & 1)  * 32;
    int koff = (mt + nt) & (NK - 1);

    // staging: thread t fills slots c0=t, c1=t+256; slot c = (row=c>>3, cs=c&7)
    // holds global chunk cg = cs ^ (row&7).
    int r0 = tid >> 3,        cg0 = (tid & 7) ^ (r0 & 7);
    int r1 = (tid + 256) >> 3, cg1 = ((tid + 256) & 7) ^ (r1 & 7);
    const unsigned short* Ag0 = xnb + (size_t)(Mb + r0) * Dr + cg0 * 8;
    const unsigned short* Ag1 = xnb + (size_t)(Mb + r1) * Dr + cg1 * 8;
    const unsigned short* Bg0 = w   + (size_t)(Nb + r0) * Dr + cg0 * 8;
    const unsigned short* Bg1 = w   + (size_t)(Nb + r1) * Dr + cg1 * 8;
    unsigned short* Al0 = &As[(size_t)tid * 8];
    unsigned short* Al1 = &As[(size_t)(tid + 256) * 8];
    unsigned short* Bl0 = &Bs[(size_t)tid * 8];
    unsigned short* Bl1 = &Bs[(size_t)(tid + 256) * 8];

    floatx4 acc[2][2] = {};

    for (int kk = 0; kk < NK; kk++) {
        int k0 = ((kk + koff) & (NK - 1)) * BK;
        gload_lds16(Ag0 + k0, Al0);
        gload_lds16(Ag1 + k0, Al1);
        gload_lds16(Bg0 + k0, Bl0);
        gload_lds16(Bg1 + k0, Bl1);
        __syncthreads();   // drains vmcnt -> LDS valid
        #pragma unroll
        for (int s = 0; s < 2; s++) {
            int ra0 = wm + lm, ra1 = wm + 16 + lm;
            int rb0 = wn + lm, rb1 = wn + 16 + lm;
            int cg = s * 4 + quad;
            bf16x8 a0 = *(const bf16x8*)&As[ra0 * BK + ((cg ^ (ra0 & 7)) * 8)];
            bf16x8 a1 = *(const bf16x8*)&As[ra1 * BK + ((cg ^ (ra1 & 7)) * 8)];
            bf16x8 b0 = *(const bf16x8*)&Bs[rb0 * BK + ((cg ^ (rb0 & 7)) * 8)];
            bf16x8 b1 = *(const bf16x8*)&Bs[rb1 * BK + ((cg ^ (rb1 & 7)) * 8)];
            acc[0][0] = __builtin_amdgcn_mfma_f32_16x16x32_bf16(a0, b0, acc[0][0], 0, 0, 0);
            acc[0][1] = __builtin_amdgcn_mfma_f32_16x16x32_bf16(a0, b1, acc[0][1], 0, 0, 0);
            acc[1][0] = __builtin_amdgcn_mfma_f32_16x16x32_bf16(a1, b0, acc[1][0], 0, 0, 0);
            acc[1][1] = __builtin_amdgcn_mfma_f32_16x16x32_bf16(a1, b1, acc[1][1], 0, 0, 0);
        }
        __syncthreads();   // before next-iter overwrite
    }

    // C/D layout: col = lane&15, row = (lane>>4)*4 + reg   [m89/m91]
    #pragma unroll
    for (int i = 0; i < 2; i++) {
        int grow0 = Mb + wm + i * 16 + quad * 4;
        #pragma unroll
        for (int jj = 0; jj < 2; jj++) {
            int gcol = Nb + wn + jj * 16 + lm;
            #pragma unroll
            for (int r = 0; r < 4; r++) {
                float v = acc[i][jj][r];
                int row = grow0 + r;
                if (gcol < Dr) {
                    dt[(size_t)row * Dr + gcol] = f2bf(softplus_f(v + b_dt[gcol]));
                } else if (gcol < Dr + Nr) {
                    bin[(size_t)row * Nr + (gcol - Dr)] = v;
                } else if (gcol < Dr + 2*Nr) {
                    cin[(size_t)row * Nr + (gcol - Dr - Nr)] = v;
                }
            }
        }
    }
}

// ---------------- K3: fused cooperative scan (flat 1-D grid, 512 blocks) ----------------
__global__ __launch_bounds__(256, 2) void scan_fused_kernel(
        const unsigned short* __restrict__ dtb,
        const unsigned short* __restrict__ xnb,
        const float* __restrict__ bin,
        const float* __restrict__ cin,
        const float* __restrict__ A_log,
        const float* __restrict__ x,
        const float* __restrict__ Dp,
        float* __restrict__ Pws,
        float* __restrict__ hendws,
        float* __restrict__ hinws,
        float* __restrict__ out) {
    cg::grid_group grid = cg::this_grid();
    int tid  = threadIdx.x;
    int bid  = blockIdx.x;            // 0..511
    int dblk = bid & 3;
    int ch   = (bid >> 2) & 63;
    int b    = bid >> 8;
    int d    = dblk * 256 + tid;
    size_t rowbase = (size_t)b * Lr + ch * CHUNK;

    float ac[16];
    #pragma unroll
    for (int i = 0; i < 4; i++) {
        float4 t = ((const float4*)(A_log + (size_t)d * Nr))[i];
        ac[i*4+0] = -__expf(t.x);
        ac[i*4+1] = -__expf(t.y);
        ac[i*4+2] = -__expf(t.z);
        ac[i*4+3] = -__expf(t.w);
    }

    __shared__ float lb[CHUNK * Nr];
    __shared__ float lc[CHUNK * Nr];
    for (int i = tid; i < CHUNK * Nr; i += 256) {
        lb[i] = bin[rowbase * Nr + i];
        lc[i] = cin[rowbase * Nr + i];
    }
    __syncthreads();

    // retained chunk inputs (live across both passes and both grid syncs)
    float dtv[CHUNK], xv[CHUNK];
    {
        const unsigned short* dtp = dtb + rowbase * Dr + d;
        const unsigned short* xp  = xnb + rowbase * Dr + d;
        #pragma unroll
        for (int t = 0; t < CHUNK; t++) {
            dtv[t] = bf2f(dtp[(size_t)t * Dr]);
            xv[t]  = bf2f(xp[(size_t)t * Dr]);
        }
    }

    // ---- phase 1: local scan, emit P + h_end ([b][ch][n][d] layout) ----
    float h[16];
    #pragma unroll
    for (int n = 0; n < 16; n++) h[n] = 0.f;
    float S = 0.f;
    #pragma unroll
    for (int t = 0; t < CHUNK; t++) {
        float dv = dtv[t];
        S += dv;
        float cm = dv * xv[t];
        const float4* br4 = (const float4*)(lb + t * Nr);
        float4 q0 = br4[0], q1 = br4[1], q2 = br4[2], q3 = br4[3];
        float bb[16] = {q0.x,q0.y,q0.z,q0.w, q1.x,q1.y,q1.z,q1.w,
                        q2.x,q2.y,q2.z,q2.w, q3.x,q3.y,q3.z,q3.w};
        #pragma unroll
        for (int n = 0; n < 16; n++)
            h[n] = __expf(dv * ac[n]) * h[n] + cm * bb[n];
    }
    size_t obase = ((size_t)(b * NCH + ch) * Nr) * Dr + d;
    #pragma unroll
    for (int n = 0; n < 16; n++) {
        Pws[obase + (size_t)n * Dr]    = __expf(S * ac[n]);
        hendws[obase + (size_t)n * Dr] = h[n];
    }

    grid.sync();

    // ---- phase 2: sequential combine over chunks (first 128 blocks) ----
    if (bid < 128) {
        int id = bid * 256 + tid;         // B*N*D = 32768
        int b2 = id >> 14;
        int dn = id & 16383;              // n*Dr + d
        size_t base = ((size_t)b2 * NCH) * (Nr * Dr) + dn;
        float hin = 0.f;
        for (int cb = 0; cb < NCH; cb += 4) {
            float p[4], he[4];
            #pragma unroll
            for (int u = 0; u < 4; u++) {
                size_t idx = base + (size_t)(cb + u) * (Nr * Dr);
                p[u]  = Pws[idx];
                he[u] = hendws[idx];
            }
            #pragma unroll
            for (int u = 0; u < 4; u++) {
                size_t idx = base + (size_t)(cb + u) * (Nr * Dr);
                hinws[idx] = hin;
                hin = p[u] * hin + he[u];
            }
        }
    }

    grid.sync();

    // ---- phase 3: re-scan with h_in (retained dtv/xv), emit y + D*residual ----
    #pragma unroll
    for (int n = 0; n < 16; n++) h[n] = hinws[obase + (size_t)n * Dr];
    float dp = Dp[d];
    const float* xr = x   + rowbase * Dr + d;
    float* op       = out + rowbase * Dr + d;

    for (int tb = 0; tb < CHUNK; tb += 4) {
        float xr4[4];
        #pragma unroll
        for (int u = 0; u < 4; u++) xr4[u] = xr[(size_t)(tb + u) * Dr];
        #pragma unroll
        for (int u = 0; u < 4; u++) {
            int t = tb + u;
            float dv = dtv[t];
            float cm = dv * xv[t];
            const float4* br4 = (const float4*)(lb + t * Nr);
            const float4* cr4 = (const float4*)(lc + t * Nr);
            float4 q0 = br4[0], q1 = br4[1], q2 = br4[2], q3 = br4[3];
            float4 r0 = cr4[0], r1 = cr4[1], r2 = cr4[2], r3 = cr4[3];
            float bb[16] = {q0.x,q0.y,q0.z,q0.w, q1.x,q1.y,q1.z,q1.w,
                            q2.x,q2.y,q2.z,q2.w, q3.x,q3.y,q3.z,q3.w};
            float cc[16] = {r0.x,r0.y,r0.z,r0.w, r1.x,r1.y,r1.z,r1.w,
                            r2.x,r2.y,r2.z,r2.w, r3.x,r3.y,r3.z,r3.w};
            float y = 0.f;
            #pragma unroll
            for (int n = 0; n < 16; n++) {
                h[n] = __expf(dv * ac[n]) * h[n] + cm * bb[n];
                y += cc[n] * h[n];
            }
            op[(size_t)t * Dr] = y + dp * xr4[u];
        }
    }
}

// ---------------- fallback scan kernels (R8-proven, bf16 dt) ----------------
__global__ __launch_bounds__(256) void scan1_kernel(const unsigned short* __restrict__ dtb,
                                                    const unsigned short* __restrict__ xnb,
                                                    const float* __restrict__ bin,
                                                    const float* __restrict__ A_log,
                                                    float* __restrict__ Pws,
                                                    float* __restrict__ hendws) {
    int d  = blockIdx.x * 256 + threadIdx.x;
    int ch = blockIdx.y;
    int b  = blockIdx.z;
    size_t rowbase = (size_t)b * Lr + ch * CHUNK;

    float ac[16];
    #pragma unroll
    for (int i = 0; i < 4; i++) {
        float4 t = ((const float4*)(A_log + (size_t)d * Nr))[i];
        ac[i*4+0] = -__expf(t.x);
        ac[i*4+1] = -__expf(t.y);
        ac[i*4+2] = -__expf(t.z);
        ac[i*4+3] = -__expf(t.w);
    }

    __shared__ float lb[CHUNK * Nr];
    for (int i = threadIdx.x; i < CHUNK * Nr; i += 256)
        lb[i] = bin[rowbase * Nr + i];
    __syncthreads();

    float h[16];
    #pragma unroll
    for (int n = 0; n < 16; n++) h[n] = 0.f;
    float S = 0.f;

    const unsigned short* dtp = dtb + rowbase * Dr + d;
    const unsigned short* xp  = xnb + rowbase * Dr + d;

    for (int tb = 0; tb < CHUNK; tb += 4) {
        float dt4[4], xv4[4];
        #pragma unroll
        for (int u = 0; u < 4; u++) {
            dt4[u] = bf2f(dtp[(size_t)(tb + u) * Dr]);
            xv4[u] = bf2f(xp[(size_t)(tb + u) * Dr]);
        }
        #pragma unroll
        for (int u = 0; u < 4; u++) {
            float dv = dt4[u];
            S += dv;
            float cm = dv * xv4[u];
            const float4* br4 = (const float4*)(lb + (tb + u) * Nr);
            float4 q0 = br4[0], q1 = br4[1], q2 = br4[2], q3 = br4[3];
            float bb[16] = {q0.x,q0.y,q0.z,q0.w, q1.x,q1.y,q1.z,q1.w,
                            q2.x,q2.y,q2.z,q2.w, q3.x,q3.y,q3.z,q3.w};
            #pragma unroll
            for (int n = 0; n < 16; n++)
                h[n] = __expf(dv * ac[n]) * h[n] + cm * bb[n];
        }
    }

    size_t obase = ((size_t)(b * NCH + ch) * Nr) * Dr + d;
    #pragma unroll
    for (int n = 0; n < 16; n++) {
        Pws[obase + (size_t)n * Dr]    = __expf(S * ac[n]);
        hendws[obase + (size_t)n * Dr] = h[n];
    }
}

__global__ __launch_bounds__(256) void combine_kernel(const float* __restrict__ Pws,
                                                      const float* __restrict__ hendws,
                                                      float* __restrict__ hinws) {
    int id = blockIdx.x * 256 + threadIdx.x;  // B*N*D = 32768
    int b  = id >> 14;
    int dn = id & 16383;
    size_t base = ((size_t)b * NCH) * (Nr * Dr) + dn;
    float hin = 0.f;
    for (int cb = 0; cb < NCH; cb += 4) {
        float p[4], he[4];
        #pragma unroll
        for (int u = 0; u < 4; u++) {
            size_t idx = base + (size_t)(cb + u) * (Nr * Dr);
            p[u]  = Pws[idx];
            he[u] = hendws[idx];
        }
        #pragma unroll
        for (int u = 0; u < 4; u++) {
            size_t idx = base + (size_t)(cb + u) * (Nr * Dr);
            hinws[idx] = hin;
            hin = p[u] * hin + he[u];
        }
    }
}

__global__ __launch_bounds__(256) void scan2_kernel(const unsigned short* __restrict__ dtb,
                                                    const unsigned short* __restrict__ xnb,
                                                    const float* __restrict__ bin,
                                                    const float* __restrict__ cin,
                                                    const float* __restrict__ A_log,
                                                    const float* __restrict__ hinws,
                                                    const float* __restrict__ x,
                                                    const float* __restrict__ Dp,
                                                    float* __restrict__ out) {
    int d  = blockIdx.x * 256 + threadIdx.x;
    int ch = blockIdx.y;
    int b  = blockIdx.z;
    size_t rowbase = (size_t)b * Lr + ch * CHUNK;

    float ac[16];
    #pragma unroll
    for (int i = 0; i < 4; i++) {
        float4 t = ((const float4*)(A_log + (size_t)d * Nr))[i];
        ac[i*4+0] = -__expf(t.x);
        ac[i*4+1] = -__expf(t.y);
        ac[i*4+2] = -__expf(t.z);
        ac[i*4+3] = -__expf(t.w);
    }

    __shared__ float lb[CHUNK * Nr];
    __shared__ float lc[CHUNK * Nr];
    for (int i = threadIdx.x; i < CHUNK * Nr; i += 256) {
        lb[i] = bin[rowbase * Nr + i];
        lc[i] = cin[rowbase * Nr + i];
    }
    __syncthreads();

    size_t obase = ((size_t)(b * NCH + ch) * Nr) * Dr + d;
    float h[16];
    #pragma unroll
    for (int n = 0; n < 16; n++) h[n] = hinws[obase + (size_t)n * Dr];

    float dp = Dp[d];
    const unsigned short* dtp = dtb + rowbase * Dr + d;
    const unsigned short* xp  = xnb + rowbase * Dr + d;
    const float* xr           = x   + rowbase * Dr + d;
    float* op                 = out + rowbase * Dr + d;

    for (int tb = 0; tb < CHUNK; tb += 4) {
        float dt4[4], xv4[4], xr4[4];
        #pragma unroll
        for (int u = 0; u < 4; u++) {
            dt4[u] = bf2f(dtp[(size_t)(tb + u) * Dr]);
            xv4[u] = bf2f(xp[(size_t)(tb + u) * Dr]);
            xr4[u] = xr[(size_t)(tb + u) * Dr];
        }
        #pragma unroll
        for (int u = 0; u < 4; u++) {
            float dv = dt4[u];
            float cm = dv * xv4[u];
            const float4* br4 = (const float4*)(lb + (tb + u) * Nr);
            const float4* cr4 = (const float4*)(lc + (tb + u) * Nr);
            float4 q0 = br4[0], q1 = br4[1], q2 = br4[2], q3 = br4[3];
            float4 r0 = cr4[0], r1 = cr4[1], r2 = cr4[2], r3 = cr4[3];
            float bb[16] = {q0.x,q0.y,q0.z,q0.w, q1.x,q1.y,q1.z,q1.w,
                            q2.x,q2.y,q2.z,q2.w, q3.x,q3.y,q3.z,q3.w};
            float cc[16] = {r0.x,r0.y,r0.z,r0.w, r1.x,r1.y,r1.z,r1.w,
                            r2.x,r2.y,r2.z,r2.w, r3.x,r3.y,r3.z,r3.w};
            float y = 0.f;
            #pragma unroll
            for (int n = 0; n < 16; n++) {
                h[n] = __expf(dv * ac[n]) * h[n] + cm * bb[n];
                y += cc[n] * h[n];
            }
            op[(size_t)(tb + u) * Dr] = y + dp * xr4[u];
        }
    }
}

// ---------------- host ----------------
extern "C" void kernel_launch(void* const* d_in, const int* in_sizes, int n_in,
                              void* d_out, int out_size, void* d_ws, size_t ws_size,
                              hipStream_t stream) {
    const float* x      = (const float*)d_in[0];
    const float* W_dt   = (const float*)d_in[1];
    const float* b_dt   = (const float*)d_in[2];
    const float* W_B    = (const float*)d_in[3];
    const float* W_C    = (const float*)d_in[4];
    const float* Dparam = (const float*)d_in[5];
    const float* A_log  = (const float*)d_in[6];
    const float* gamma  = (const float*)d_in[7];
    const float* beta   = (const float*)d_in[8];
    float* out = (float*)d_out;

    char* ws = (char*)d_ws;
    unsigned short* xnb  = (unsigned short*)(ws);                     // 8 MB
    unsigned short* wcat = (unsigned short*)(ws + 8388608);           // 2.125 MB
    unsigned short* dtb  = (unsigned short*)(ws + 10616832);          // 8 MB (bf16)
    float*          bin  = (float*)(ws + 19005440);                   // 256 KB
    float*          cin  = (float*)(ws + 19267584);                   // 256 KB
    float*          Pws  = (float*)(ws + 19529728);                   // 8 MB
    float*          hend = (float*)(ws + 27918336);                   // 8 MB
    float*          hin  = (float*)(ws + 36306944);                   // 8 MB  (total ~45 MB)

    ln_pack_kernel<<<M_ROWS + (NPAD * Dr) / 256, 256, 0, stream>>>(
        x, gamma, beta, xnb, W_dt, W_B, W_C, wcat);
    gemm_kernel<<<(M_ROWS / BM) * (NPAD / BN), 256, 0, stream>>>(xnb, wcat, b_dt, dtb, bin, cin);

    // cooperative fused scan if >=2 blocks/CU fit (512 blocks on 256 CUs);
    // otherwise (or on launch error) fall back to the proven 3-kernel path.
    int maxBlk = 0;
    hipError_t qerr = hipOccupancyMaxActiveBlocksPerMultiprocessor(
        &maxBlk, (const void*)scan_fused_kernel, 256, 0);
    bool coop_done = false;
    if (qerr == hipSuccess && maxBlk >= 2) {
        void* args[] = {
            (void*)&dtb, (void*)&xnb, (void*)&bin, (void*)&cin, (void*)&A_log,
            (void*)&x, (void*)&Dparam, (void*)&Pws, (void*)&hend, (void*)&hin, (void*)&out
        };
        hipError_t e = hipLaunchCooperativeKernel((const void*)scan_fused_kernel,
                                                  dim3(512), dim3(256),
                                                  args, 0, stream);
        coop_done = (e == hipSuccess);
    }
    if (!coop_done) {
        dim3 sgrid(Dr / 256, NCH, Bsz);
        scan1_kernel<<<sgrid, 256, 0, stream>>>(dtb, xnb, bin, A_log, Pws, hend);
        combine_kernel<<<(Bsz * Dr * Nr) / 256, 256, 0, stream>>>(Pws, hend, hin);
        scan2_kernel<<<sgrid, 256, 0, stream>>>(dtb, xnb, bin, cin, A_log, hin, x, Dparam, out);
    }
}

// Round 11
// 149.598 us; speedup vs baseline: 1.0668x; 1.0668x over previous
//
#include <hip/hip_runtime.h>
#include <cstddef>

// Problem constants
#define Bsz 2
#define Lr  2048
#define Dr  1024
#define Nr  16
#define M_ROWS (Bsz*Lr)          // 4096
#define NPAD   1088              // padded (W_dt | W_B | W_C | zeros), 17 tiles of 64
#define CHUNK  16
#define NCH    (Lr/CHUNK)        // 128

#define BM 64
#define BN 64
#define BK 64
#define NK (Dr/BK)               // 16 K-iterations

typedef __attribute__((ext_vector_type(8))) __bf16 bf16x8;
typedef __attribute__((ext_vector_type(4))) float floatx4;

__device__ __forceinline__ unsigned short f2bf(float f) {
    unsigned u = __float_as_uint(f);
    u += 0x7fffu + ((u >> 16) & 1u);
    return (unsigned short)(u >> 16);
}

__device__ __forceinline__ float bf2f(unsigned short u) {
    return __uint_as_float(((unsigned)u) << 16);
}

__device__ __forceinline__ float softplus_f(float x) {
    // abs threshold is 0.905 -> fast log is fine
    if (x > 0.f) return x + __logf(1.f + __expf(-x));
    return __logf(1.f + __expf(x));
}

__device__ __forceinline__ void gload_lds16(const unsigned short* g, unsigned short* l) {
    __builtin_amdgcn_global_load_lds((const __attribute__((address_space(1))) void*)g,
                                     (__attribute__((address_space(3))) void*)l, 16, 0, 0);
}

// ---------------- K0: fused LayerNorm (blocks 0..4095) + weight-pack (rest) ----------------
__global__ __launch_bounds__(256) void ln_pack_kernel(const float* __restrict__ x,
                                                      const float* __restrict__ gamma,
                                                      const float* __restrict__ beta,
                                                      unsigned short* __restrict__ xnb,
                                                      const float* __restrict__ Wdt,
                                                      const float* __restrict__ WB,
                                                      const float* __restrict__ WC,
                                                      unsigned short* __restrict__ Wcat) {
    if (blockIdx.x >= M_ROWS) {
        int i = (blockIdx.x - M_ROWS) * 256 + threadIdx.x;  // over NPAD*Dr
        int row = i >> 10;
        int col = i & 1023;
        float v;
        if (row < Dr)                 v = Wdt[i];
        else if (row < Dr + Nr)       v = WB[(row - Dr) * Dr + col];
        else if (row < Dr + 2*Nr)     v = WC[(row - Dr - Nr) * Dr + col];
        else                          v = 0.f;
        Wcat[i] = f2bf(v);
        return;
    }
    int row = blockIdx.x;
    int tid = threadIdx.x;
    const float4* xr = (const float4*)(x + (size_t)row * Dr);
    float4 v = xr[tid];
    float s  = v.x + v.y + v.z + v.w;
    float ss = v.x*v.x + v.y*v.y + v.z*v.z + v.w*v.w;
    #pragma unroll
    for (int off = 32; off > 0; off >>= 1) {
        s  += __shfl_down(s, off);
        ss += __shfl_down(ss, off);
    }
    __shared__ float red[8];
    int wid = tid >> 6;
    if ((tid & 63) == 0) { red[wid*2] = s; red[wid*2+1] = ss; }
    __syncthreads();
    if (tid == 0) {
        float S = 0.f, SS = 0.f;
        #pragma unroll
        for (int w = 0; w < 4; w++) { S += red[w*2]; SS += red[w*2+1]; }
        float mu  = S * (1.f/Dr);
        float var = SS * (1.f/Dr) - mu*mu;
        red[0] = mu;
        red[1] = rsqrtf(var + 1e-5f);
    }
    __syncthreads();
    float mu = red[0], rs = red[1];
    float4 g = ((const float4*)gamma)[tid], bt = ((const float4*)beta)[tid];
    float4 o;
    o.x = (v.x - mu) * rs * g.x + bt.x;
    o.y = (v.y - mu) * rs * g.y + bt.y;
    o.z = (v.z - mu) * rs * g.z + bt.z;
    o.w = (v.w - mu) * rs * g.w + bt.w;
    ushort4 ob;
    ob.x = f2bf(o.x); ob.y = f2bf(o.y); ob.z = f2bf(o.z); ob.w = f2bf(o.w);
    ((ushort4*)(xnb + (size_t)row * Dr))[tid] = ob;
}

// ---------------- K2: MFMA GEMM [M_ROWS x NPAD] = xnb @ Wcat^T ----------------
// R10 structure: 4-wave 64x64, BK=64 (16 barrier drains), XOR-swizzled LDS
// (conflict-free frag reads), XCD swizzle, k-stagger, bf16 dt output.
__global__ __launch_bounds__(256) void gemm_kernel(const unsigned short* __restrict__ xnb,
                                                   const unsigned short* __restrict__ w,
                                                   const float* __restrict__ b_dt,
                                                   unsigned short* __restrict__ dt,
                                                   float* __restrict__ bin,
                                                   float* __restrict__ cin) {
    __shared__ unsigned short As[BM * BK];  // 8 KB, swizzled [64 rows][8 slots of 8]
    __shared__ unsigned short Bs[BN * BK];  // 8 KB
    int tid  = threadIdx.x;
    int wave = tid >> 6;
    int lane = tid & 63;
    int lm   = lane & 15;
    int quad = lane >> 4;
    int bid  = blockIdx.x;             // 1088 blocks = 8 XCD-lanes x 136
    int xcd  = bid & 7;
    int j0   = bid >> 3;               // 0..135
    int nt   = j0 % 17;
    int mt   = (j0 / 17) * 8 + xcd;    // 0..63
    int Mb = mt * BM;
    int Nb = nt * BN;
    int wm = (wave >> 1) * 32;
    int wn = (wave & 1)  * 32;
    int koff = (mt + nt) & (NK - 1);

    // staging: thread t fills slots c0=t, c1=t+256; slot c = (row=c>>3, cs=c&7)
    // holds global chunk cg = cs ^ (row&7).
    int r0 = tid >> 3,         cg0 = (tid & 7) ^ (r0 & 7);
    int r1 = (tid + 256) >> 3, cg1 = ((tid + 256) & 7) ^ (r1 & 7);
    const unsigned short* Ag0 = xnb + (size_t)(Mb + r0) * Dr + cg0 * 8;
    const unsigned short* Ag1 = xnb + (size_t)(Mb + r1) * Dr + cg1 * 8;
    const unsigned short* Bg0 = w   + (size_t)(Nb + r0) * Dr + cg0 * 8;
    const unsigned short* Bg1 = w   + (size_t)(Nb + r1) * Dr + cg1 * 8;
    unsigned short* Al0 = &As[(size_t)tid * 8];
    unsigned short* Al1 = &As[(size_t)(tid + 256) * 8];
    unsigned short* Bl0 = &Bs[(size_t)tid * 8];
    unsigned short* Bl1 = &Bs[(size_t)(tid + 256) * 8];

    floatx4 acc[2][2] = {};

    for (int kk = 0; kk < NK; kk++) {
        int k0 = ((kk + koff) & (NK - 1)) * BK;
        gload_lds16(Ag0 + k0, Al0);
        gload_lds16(Ag1 + k0, Al1);
        gload_lds16(Bg0 + k0, Bl0);
        gload_lds16(Bg1 + k0, Bl1);
        __syncthreads();   // drains vmcnt -> LDS valid
        #pragma unroll
        for (int s = 0; s < 2; s++) {
            int ra0 = wm + lm, ra1 = wm + 16 + lm;
            int rb0 = wn + lm, rb1 = wn + 16 + lm;
            int cg = s * 4 + quad;
            bf16x8 a0 = *(const bf16x8*)&As[ra0 * BK + ((cg ^ (ra0 & 7)) * 8)];
            bf16x8 a1 = *(const bf16x8*)&As[ra1 * BK + ((cg ^ (ra1 & 7)) * 8)];
            bf16x8 b0 = *(const bf16x8*)&Bs[rb0 * BK + ((cg ^ (rb0 & 7)) * 8)];
            bf16x8 b1 = *(const bf16x8*)&Bs[rb1 * BK + ((cg ^ (rb1 & 7)) * 8)];
            acc[0][0] = __builtin_amdgcn_mfma_f32_16x16x32_bf16(a0, b0, acc[0][0], 0, 0, 0);
            acc[0][1] = __builtin_amdgcn_mfma_f32_16x16x32_bf16(a0, b1, acc[0][1], 0, 0, 0);
            acc[1][0] = __builtin_amdgcn_mfma_f32_16x16x32_bf16(a1, b0, acc[1][0], 0, 0, 0);
            acc[1][1] = __builtin_amdgcn_mfma_f32_16x16x32_bf16(a1, b1, acc[1][1], 0, 0, 0);
        }
        __syncthreads();   // before next-iter overwrite
    }

    // C/D layout: col = lane&15, row = (lane>>4)*4 + reg   [m89/m91]
    #pragma unroll
    for (int i = 0; i < 2; i++) {
        int grow0 = Mb + wm + i * 16 + quad * 4;
        #pragma unroll
        for (int jj = 0; jj < 2; jj++) {
            int gcol = Nb + wn + jj * 16 + lm;
            #pragma unroll
            for (int r = 0; r < 4; r++) {
                float v = acc[i][jj][r];
                int row = grow0 + r;
                if (gcol < Dr) {
                    dt[(size_t)row * Dr + gcol] = f2bf(softplus_f(v + b_dt[gcol]));
                } else if (gcol < Dr + Nr) {
                    bin[(size_t)row * Nr + (gcol - Dr)] = v;
                } else if (gcol < Dr + 2*Nr) {
                    cin[(size_t)row * Nr + (gcol - Dr - Nr)] = v;
                }
            }
        }
    }
}

// ---------------- K3: scan pass 1 (per-chunk local scan; emit P, h_end bf16) ----------------
// CHUNK=16 -> 128 chunks -> 1024 blocks = 16 waves/CU (2x the CHUNK=32 occupancy;
// R10 profile: scans latency-bound at 22% occupancy, 13% VALU, 9% HBM).
__global__ __launch_bounds__(256) void scan1_kernel(const unsigned short* __restrict__ dtb,
                                                    const unsigned short* __restrict__ xnb,
                                                    const float* __restrict__ bin,
                                                    const float* __restrict__ A_log,
                                                    unsigned short* __restrict__ Pws,
                                                    unsigned short* __restrict__ hendws) {
    int tid = threadIdx.x;
    int d  = blockIdx.x * 256 + tid;
    int ch = blockIdx.y;
    int b  = blockIdx.z;
    size_t rowbase = (size_t)b * Lr + ch * CHUNK;

    float ac[16];
    #pragma unroll
    for (int i = 0; i < 4; i++) {
        float4 t = ((const float4*)(A_log + (size_t)d * Nr))[i];
        ac[i*4+0] = -__expf(t.x);
        ac[i*4+1] = -__expf(t.y);
        ac[i*4+2] = -__expf(t.z);
        ac[i*4+3] = -__expf(t.w);
    }

    __shared__ float lb[CHUNK * Nr];   // 256 floats: one per thread
    lb[tid] = bin[rowbase * Nr + tid];
    __syncthreads();

    // full register batch: 32 loads in flight
    float dtv[CHUNK], xv[CHUNK];
    {
        const unsigned short* dtp = dtb + rowbase * Dr + d;
        const unsigned short* xp  = xnb + rowbase * Dr + d;
        #pragma unroll
        for (int t = 0; t < CHUNK; t++) {
            dtv[t] = bf2f(dtp[(size_t)t * Dr]);
            xv[t]  = bf2f(xp[(size_t)t * Dr]);
        }
    }

    float h[16];
    #pragma unroll
    for (int n = 0; n < 16; n++) h[n] = 0.f;
    float S = 0.f;

    #pragma unroll
    for (int t = 0; t < CHUNK; t++) {
        float dv = dtv[t];
        S += dv;
        float cm = dv * xv[t];
        const float4* br4 = (const float4*)(lb + t * Nr);
        float4 q0 = br4[0], q1 = br4[1], q2 = br4[2], q3 = br4[3];
        float bb[16] = {q0.x,q0.y,q0.z,q0.w, q1.x,q1.y,q1.z,q1.w,
                        q2.x,q2.y,q2.z,q2.w, q3.x,q3.y,q3.z,q3.w};
        #pragma unroll
        for (int n = 0; n < 16; n++)
            h[n] = __expf(dv * ac[n]) * h[n] + cm * bb[n];
    }

    size_t obase = ((size_t)(b * NCH + ch) * Nr) * Dr + d;   // [b][ch][n][d]
    #pragma unroll
    for (int n = 0; n < 16; n++) {
        Pws[obase + (size_t)n * Dr]    = f2bf(__expf(S * ac[n]));
        hendws[obase + (size_t)n * Dr] = f2bf(h[n]);
    }
}

// ---------------- K4: combine chunk states sequentially (batch-8, bf16 state) ----------------
__global__ __launch_bounds__(256) void combine_kernel(const unsigned short* __restrict__ Pws,
                                                      const unsigned short* __restrict__ hendws,
                                                      unsigned short* __restrict__ hinws) {
    int id = blockIdx.x * 256 + threadIdx.x;  // B*N*D = 32768
    int b  = id >> 14;
    int dn = id & 16383;                      // n*Dr + d
    size_t base = ((size_t)b * NCH) * (Nr * Dr) + dn;
    float hin = 0.f;
    for (int cb = 0; cb < NCH; cb += 8) {
        float p[8], he[8];
        #pragma unroll
        for (int u = 0; u < 8; u++) {
            size_t idx = base + (size_t)(cb + u) * (Nr * Dr);
            p[u]  = bf2f(Pws[idx]);
            he[u] = bf2f(hendws[idx]);
        }
        #pragma unroll
        for (int u = 0; u < 8; u++) {
            size_t idx = base + (size_t)(cb + u) * (Nr * Dr);
            hinws[idx] = f2bf(hin);
            hin = p[u] * hin + he[u];
        }
    }
}

// ---------------- K5: scan pass 2 (re-scan with h_in; emit y + D*residual) ----------------
__global__ __launch_bounds__(256) void scan2_kernel(const unsigned short* __restrict__ dtb,
                                                    const unsigned short* __restrict__ xnb,
                                                    const float* __restrict__ bin,
                                                    const float* __restrict__ cin,
                                                    const float* __restrict__ A_log,
                                                    const unsigned short* __restrict__ hinws,
                                                    const float* __restrict__ x,
                                                    const float* __restrict__ Dp,
                                                    float* __restrict__ out) {
    int tid = threadIdx.x;
    int d  = blockIdx.x * 256 + tid;
    int ch = blockIdx.y;
    int b  = blockIdx.z;
    size_t rowbase = (size_t)b * Lr + ch * CHUNK;

    float ac[16];
    #pragma unroll
    for (int i = 0; i < 4; i++) {
        float4 t = ((const float4*)(A_log + (size_t)d * Nr))[i];
        ac[i*4+0] = -__expf(t.x);
        ac[i*4+1] = -__expf(t.y);
        ac[i*4+2] = -__expf(t.z);
        ac[i*4+3] = -__expf(t.w);
    }

    __shared__ float lb[CHUNK * Nr];
    __shared__ float lc[CHUNK * Nr];
    lb[tid] = bin[rowbase * Nr + tid];
    lc[tid] = cin[rowbase * Nr + tid];
    __syncthreads();

    // full register batches in flight
    float dtv[CHUNK], xv[CHUNK];
    {
        const unsigned short* dtp = dtb + rowbase * Dr + d;
        const unsigned short* xp  = xnb + rowbase * Dr + d;
        #pragma unroll
        for (int t = 0; t < CHUNK; t++) {
            dtv[t] = bf2f(dtp[(size_t)t * Dr]);
            xv[t]  = bf2f(xp[(size_t)t * Dr]);
        }
    }

    size_t obase = ((size_t)(b * NCH + ch) * Nr) * Dr + d;
    float h[16];
    #pragma unroll
    for (int n = 0; n < 16; n++) h[n] = bf2f(hinws[obase + (size_t)n * Dr]);

    float dp = Dp[d];
    const float* xr = x   + rowbase * Dr + d;
    float* op       = out + rowbase * Dr + d;

    for (int tb = 0; tb < CHUNK; tb += 4) {
        float xr4[4];
        #pragma unroll
        for (int u = 0; u < 4; u++) xr4[u] = xr[(size_t)(tb + u) * Dr];
        #pragma unroll
        for (int u = 0; u < 4; u++) {
            int t = tb + u;
            float dv = dtv[t];
            float cm = dv * xv[t];
            const float4* br4 = (const float4*)(lb + t * Nr);
            const float4* cr4 = (const float4*)(lc + t * Nr);
            float4 q0 = br4[0], q1 = br4[1], q2 = br4[2], q3 = br4[3];
            float4 r0 = cr4[0], r1 = cr4[1], r2 = cr4[2], r3 = cr4[3];
            float bb[16] = {q0.x,q0.y,q0.z,q0.w, q1.x,q1.y,q1.z,q1.w,
                            q2.x,q2.y,q2.z,q2.w, q3.x,q3.y,q3.z,q3.w};
            float cc[16] = {r0.x,r0.y,r0.z,r0.w, r1.x,r1.y,r1.z,r1.w,
                            r2.x,r2.y,r2.z,r2.w, r3.x,r3.y,r3.z,r3.w};
            float y = 0.f;
            #pragma unroll
            for (int n = 0; n < 16; n++) {
                h[n] = __expf(dv * ac[n]) * h[n] + cm * bb[n];
                y += cc[n] * h[n];
            }
            op[(size_t)t * Dr] = y + dp * xr4[u];
        }
    }
}

// ---------------- host ----------------
extern "C" void kernel_launch(void* const* d_in, const int* in_sizes, int n_in,
                              void* d_out, int out_size, void* d_ws, size_t ws_size,
                              hipStream_t stream) {
    const float* x      = (const float*)d_in[0];
    const float* W_dt   = (const float*)d_in[1];
    const float* b_dt   = (const float*)d_in[2];
    const float* W_B    = (const float*)d_in[3];
    const float* W_C    = (const float*)d_in[4];
    const float* Dparam = (const float*)d_in[5];
    const float* A_log  = (const float*)d_in[6];
    const float* gamma  = (const float*)d_in[7];
    const float* beta   = (const float*)d_in[8];
    float* out = (float*)d_out;

    char* ws = (char*)d_ws;
    unsigned short* xnb  = (unsigned short*)(ws);                     // 8 MB
    unsigned short* wcat = (unsigned short*)(ws + 8388608);           // 2.125 MB
    unsigned short* dtb  = (unsigned short*)(ws + 10616832);          // 8 MB (bf16)
    float*          bin  = (float*)(ws + 19005440);                   // 256 KB
    float*          cin  = (float*)(ws + 19267584);                   // 256 KB
    unsigned short* Pws  = (unsigned short*)(ws + 19529728);          // 8 MB (bf16, 128 chunks)
    unsigned short* hend = (unsigned short*)(ws + 27918336);          // 8 MB
    unsigned short* hin  = (unsigned short*)(ws + 36306944);          // 8 MB  (total ~45 MB)

    ln_pack_kernel<<<M_ROWS + (NPAD * Dr) / 256, 256, 0, stream>>>(
        x, gamma, beta, xnb, W_dt, W_B, W_C, wcat);
    gemm_kernel<<<(M_ROWS / BM) * (NPAD / BN), 256, 0, stream>>>(xnb, wcat, b_dt, dtb, bin, cin);
    dim3 sgrid(Dr / 256, NCH, Bsz);
    scan1_kernel<<<sgrid, 256, 0, stream>>>(dtb, xnb, bin, A_log, Pws, hend);
    combine_kernel<<<(Bsz * Dr * Nr) / 256, 256, 0, stream>>>(Pws, hend, hin);
    scan2_kernel<<<sgrid, 256, 0, stream>>>(dtb, xnb, bin, cin, A_log, hin, x, Dparam, out);
}